// Round 1
// baseline (2146.732 us; speedup 1.0000x reference)
//
#include <hip/hip_runtime.h>
#include <math.h>

#define Bb 4
#define Ss 2048
#define Ee 1024
#define Hh 16
#define Dd 64

static constexpr int Mtot = Bb * Ss; // 8192

// ---------------------------------------------------------------------------
// GEMM: C[M,N] = A[M,K] @ W[N,K]^T + bias[N]   (torch Linear layout)
// 64x64 block tile, BK=32, 256 threads, 4x4 per thread.
// LDS stored transposed (As[k][m], Ws[k][n]) so the inner loop does two
// ds_read_b128 per 16 FMAs.
// ---------------------------------------------------------------------------
__global__ __launch_bounds__(256) void gemm_bt_bias(const float* __restrict__ A,
                                                    const float* __restrict__ W,
                                                    const float* __restrict__ bias,
                                                    float* __restrict__ C,
                                                    int M, int N, int K) {
  __shared__ float As[32][68]; // 68: row = 272B, 16B-aligned, breaks pow2 stride
  __shared__ float Ws[32][68];
  const int tid = threadIdx.x;
  const int bm  = blockIdx.x << 6;
  const int bn  = blockIdx.y << 6;
  const int tx  = tid & 15;
  const int ty  = tid >> 4;
  const int r   = tid >> 3;        // 0..31
  const int c4  = (tid & 7) << 2;  // 0,4,...,28

  const float* Ap0 = A + (size_t)(bm + r) * K + c4;
  const float* Ap1 = Ap0 + (size_t)32 * K;
  const float* Wp0 = W + (size_t)(bn + r) * K + c4;
  const float* Wp1 = Wp0 + (size_t)32 * K;

  float acc[4][4] = {};

  for (int k0 = 0; k0 < K; k0 += 32) {
    float4 a0 = *(const float4*)(Ap0 + k0);
    float4 a1 = *(const float4*)(Ap1 + k0);
    float4 w0 = *(const float4*)(Wp0 + k0);
    float4 w1 = *(const float4*)(Wp1 + k0);
    __syncthreads(); // previous iteration's LDS reads complete
    As[c4+0][r]    = a0.x; As[c4+1][r]    = a0.y; As[c4+2][r]    = a0.z; As[c4+3][r]    = a0.w;
    As[c4+0][r+32] = a1.x; As[c4+1][r+32] = a1.y; As[c4+2][r+32] = a1.z; As[c4+3][r+32] = a1.w;
    Ws[c4+0][r]    = w0.x; Ws[c4+1][r]    = w0.y; Ws[c4+2][r]    = w0.z; Ws[c4+3][r]    = w0.w;
    Ws[c4+0][r+32] = w1.x; Ws[c4+1][r+32] = w1.y; Ws[c4+2][r+32] = w1.z; Ws[c4+3][r+32] = w1.w;
    __syncthreads();
#pragma unroll
    for (int kk = 0; kk < 32; ++kk) {
      float4 av = *(const float4*)(&As[kk][ty << 2]);
      float4 wv = *(const float4*)(&Ws[kk][tx << 2]);
      float a_[4] = {av.x, av.y, av.z, av.w};
      float w_[4] = {wv.x, wv.y, wv.z, wv.w};
#pragma unroll
      for (int i = 0; i < 4; ++i)
#pragma unroll
        for (int j = 0; j < 4; ++j)
          acc[i][j] += a_[i] * w_[j];
    }
  }
  const int cn = bn + (tx << 2);
  const float4 bv = *(const float4*)(bias + cn);
#pragma unroll
  for (int i = 0; i < 4; ++i) {
    float4 o;
    o.x = acc[i][0] + bv.x;
    o.y = acc[i][1] + bv.y;
    o.z = acc[i][2] + bv.z;
    o.w = acc[i][3] + bv.w;
    *(float4*)(C + (size_t)(bm + (ty << 2) + i) * N + cn) = o;
  }
}

// ---------------------------------------------------------------------------
// Flash attention, fp32. One block per (b, h, 64-row Q tile).
// Q/K stored transposed in LDS ([d][row]) for float4 inner-loop reads.
// P round-trips LDS (transposed) for the PV product. O may alias Q: each
// block reads exactly the Q region it writes, and reads it before writing.
// ---------------------------------------------------------------------------
__global__ __launch_bounds__(256) void flash_attn(const float* Q, const float* Kp,
                                                  const float* Vp, float* O) {
  __shared__ float Qs[64][64]; // [d][r], pre-scaled by 1/sqrt(D)
  __shared__ float Ks[64][64]; // [d][c]
  __shared__ float Vs[64][64]; // [j][d]
  __shared__ float Ps[64][64]; // [j][r]
  const int tid = threadIdx.x;
  const int qt  = blockIdx.x << 6;
  const int bh  = blockIdx.y;
  const int b   = bh >> 4;
  const int h   = bh & 15;
  const size_t base = (size_t)b * Ss * Ee + (size_t)h * Dd;
  const int tx = tid & 15, ty = tid >> 4;
  const int lr = tid >> 2;        // 0..63
  const int lc = (tid & 3) << 4;  // 0,16,32,48

  { // load+scale Q tile
    const float* qp = Q + base + (size_t)(qt + lr) * Ee + lc;
#pragma unroll
    for (int i = 0; i < 4; ++i) {
      float4 v = *(const float4*)(qp + 4 * i);
      const int c = lc + 4 * i;
      Qs[c+0][lr] = v.x * 0.125f;
      Qs[c+1][lr] = v.y * 0.125f;
      Qs[c+2][lr] = v.z * 0.125f;
      Qs[c+3][lr] = v.w * 0.125f;
    }
  }

  float o[4][4] = {};
  float m_[4] = {-INFINITY, -INFINITY, -INFINITY, -INFINITY};
  float l_[4] = {0.f, 0.f, 0.f, 0.f};

  for (int kt = 0; kt < Ss; kt += 64) {
    const float* kp = Kp + base + (size_t)(kt + lr) * Ee + lc;
    const float* vp = Vp + base + (size_t)(kt + lr) * Ee + lc;
    float4 kv[4], vv[4];
#pragma unroll
    for (int i = 0; i < 4; ++i) {
      kv[i] = *(const float4*)(kp + 4 * i);
      vv[i] = *(const float4*)(vp + 4 * i);
    }
    __syncthreads(); // prev tile's Sc/PV reads of Ks/Vs/Ps complete
#pragma unroll
    for (int i = 0; i < 4; ++i) {
      const int c = lc + 4 * i;
      Ks[c+0][lr] = kv[i].x; Ks[c+1][lr] = kv[i].y;
      Ks[c+2][lr] = kv[i].z; Ks[c+3][lr] = kv[i].w;
      *(float4*)(&Vs[lr][c]) = vv[i];
    }
    __syncthreads();

    // Sc = (Q/8) K^T  -- 4x4 per thread
    float sc[4][4] = {};
#pragma unroll 8
    for (int d = 0; d < 64; ++d) {
      float4 qv = *(const float4*)(&Qs[d][ty << 2]);
      float4 kk = *(const float4*)(&Ks[d][tx << 2]);
      float qa[4] = {qv.x, qv.y, qv.z, qv.w};
      float ka[4] = {kk.x, kk.y, kk.z, kk.w};
#pragma unroll
      for (int i = 0; i < 4; ++i)
#pragma unroll
        for (int j = 0; j < 4; ++j)
          sc[i][j] += qa[i] * ka[j];
    }

    // online softmax (rows live in 16-lane shuffle groups)
#pragma unroll
    for (int i = 0; i < 4; ++i) {
      float mt = fmaxf(fmaxf(sc[i][0], sc[i][1]), fmaxf(sc[i][2], sc[i][3]));
#pragma unroll
      for (int off = 1; off < 16; off <<= 1) mt = fmaxf(mt, __shfl_xor(mt, off, 16));
      const float mn = fmaxf(m_[i], mt);
      const float alpha = __expf(m_[i] - mn);
      m_[i] = mn;
      float rs = 0.f;
#pragma unroll
      for (int j = 0; j < 4; ++j) { sc[i][j] = __expf(sc[i][j] - mn); rs += sc[i][j]; }
#pragma unroll
      for (int off = 1; off < 16; off <<= 1) rs += __shfl_xor(rs, off, 16);
      l_[i] = alpha * l_[i] + rs;
#pragma unroll
      for (int j = 0; j < 4; ++j) o[i][j] *= alpha;
    }

    // P -> LDS (transposed: Ps[k-col][q-row])
#pragma unroll
    for (int i = 0; i < 4; ++i)
#pragma unroll
      for (int j = 0; j < 4; ++j)
        Ps[(tx << 2) + j][(ty << 2) + i] = sc[i][j];
    __syncthreads();

    // O += P V
#pragma unroll 8
    for (int j0 = 0; j0 < 64; ++j0) {
      float4 pv = *(const float4*)(&Ps[j0][ty << 2]);
      float4 vvv = *(const float4*)(&Vs[j0][tx << 2]);
      float pa[4] = {pv.x, pv.y, pv.z, pv.w};
      float va[4] = {vvv.x, vvv.y, vvv.z, vvv.w};
#pragma unroll
      for (int i = 0; i < 4; ++i)
#pragma unroll
        for (int j = 0; j < 4; ++j)
          o[i][j] += pa[i] * va[j];
    }
  }

  // epilogue: normalize, write (O aliases Q region this block already consumed)
#pragma unroll
  for (int i = 0; i < 4; ++i) {
    const float inv = 1.0f / l_[i];
    float4 ov;
    ov.x = o[i][0] * inv; ov.y = o[i][1] * inv;
    ov.z = o[i][2] * inv; ov.w = o[i][3] * inv;
    *(float4*)(O + base + (size_t)(qt + (ty << 2) + i) * Ee + (tx << 2)) = ov;
  }
}

extern "C" void kernel_launch(void* const* d_in, const int* in_sizes, int n_in,
                              void* d_out, int out_size, void* d_ws, size_t ws_size,
                              hipStream_t stream) {
  const float* x  = (const float*)d_in[0];
  const float* Wq = (const float*)d_in[1];
  const float* bq = (const float*)d_in[2];
  const float* Wk = (const float*)d_in[3];
  const float* bk = (const float*)d_in[4];
  const float* Wv = (const float*)d_in[5];
  const float* bv = (const float*)d_in[6];
  const float* Wo = (const float*)d_in[7];
  const float* bo = (const float*)d_in[8];
  float* out = (float*)d_out;

  const size_t nBSE = (size_t)Bb * Ss * Ee; // 8.39M floats = 32 MB
  float* qbuf = (float*)d_ws;
  float* kbuf = qbuf + nBSE;
  float* vbuf = kbuf + nBSE;

  dim3 gg(Mtot / 64, Ee / 64);
  gemm_bt_bias<<<gg, 256, 0, stream>>>(x, Wq, bq, qbuf, Mtot, Ee, Ee);
  gemm_bt_bias<<<gg, 256, 0, stream>>>(x, Wk, bk, kbuf, Mtot, Ee, Ee);
  gemm_bt_bias<<<gg, 256, 0, stream>>>(x, Wv, bv, vbuf, Mtot, Ee, Ee);
  flash_attn<<<dim3(Ss / 64, Bb * Hh), 256, 0, stream>>>(qbuf, kbuf, vbuf, qbuf);
  gemm_bt_bias<<<gg, 256, 0, stream>>>(qbuf, Wo, bo, out, Mtot, Ee, Ee);
}

// Round 2
// 1464.988 us; speedup vs baseline: 1.4654x; 1.4654x over previous
//
#include <hip/hip_runtime.h>
#include <math.h>

#define Bb 4
#define Ss 2048
#define Ee 1024
#define Hh 16
#define Dd 64

static constexpr int Mtot = Bb * Ss; // 8192

typedef __bf16 bf16x8 __attribute__((ext_vector_type(8)));
typedef float  f32x16 __attribute__((ext_vector_type(16)));

// Truncation split: a = hi + lo with hi = top-16-bits(a) as bf16, lo = bf16(a - hi).
// a - hi is exact (high bits agree); residual after lo ~ 2^-16 * |a|.
__device__ __forceinline__ void split4(const float4 v, short4* h, short4* l) {
  unsigned u;
  u = __float_as_uint(v.x); h->x = (short)(u >> 16);
  l->x = (short)(__float_as_uint(v.x - __uint_as_float(u & 0xFFFF0000u)) >> 16);
  u = __float_as_uint(v.y); h->y = (short)(u >> 16);
  l->y = (short)(__float_as_uint(v.y - __uint_as_float(u & 0xFFFF0000u)) >> 16);
  u = __float_as_uint(v.z); h->z = (short)(u >> 16);
  l->z = (short)(__float_as_uint(v.z - __uint_as_float(u & 0xFFFF0000u)) >> 16);
  u = __float_as_uint(v.w); h->w = (short)(u >> 16);
  l->w = (short)(__float_as_uint(v.w - __uint_as_float(u & 0xFFFF0000u)) >> 16);
}

// ---------------------------------------------------------------------------
// Split-bf16 MFMA GEMM: C[M,N] = A[M,K] @ W[N,K]^T + bias[N]  (fp32 in/out)
// 128x128 block tile, BK=32, 256 threads = 4 waves, each wave 64x64 via
// 2x2 subtiles of mfma_f32_32x32x16_bf16, 3 MFMAs per product (hi*hi +
// hi*lo + lo*hi). LDS row stride 40 shorts (80 B -> 20 banks) =>
// conflict-free b128 fragment reads (verified by hand: 20*m % 32 covers all
// 8 quad positions uniformly).
// ---------------------------------------------------------------------------
__global__ __launch_bounds__(256) void gemm_mfma(const float* __restrict__ A,
                                                 const float* __restrict__ W,
                                                 const float* __restrict__ bias,
                                                 float* __restrict__ C,
                                                 int M, int N, int K) {
  __shared__ short Ah[128][40];
  __shared__ short Al[128][40];
  __shared__ short Wh[128][40];
  __shared__ short Wl[128][40];

  const int tid = threadIdx.x;
  const int bm  = blockIdx.x << 7;
  const int bn  = blockIdx.y << 7;
  const int r8  = tid >> 3;        // 0..31 staging row
  const int c8  = (tid & 7) << 2;  // 0,4,...,28 staging col (floats)
  const int lane = tid & 63;
  const int w    = tid >> 6;
  const int wm   = (w & 1) << 6;   // wave row offset in tile
  const int wn   = (w >> 1) << 6;  // wave col offset in tile
  const int m32  = lane & 31;
  const int g    = lane >> 5;      // k-group (0/1)

  const float* Ap = A + (size_t)(bm + r8) * K + c8;
  const float* Wp = W + (size_t)(bn + r8) * K + c8;

  f32x16 acc[2][2] = {};

  for (int k0 = 0; k0 < K; k0 += 32) {
    float4 av[4], wv[4];
#pragma unroll
    for (int p = 0; p < 4; ++p) {
      av[p] = *(const float4*)(Ap + (size_t)(32 * p) * K + k0);
      wv[p] = *(const float4*)(Wp + (size_t)(32 * p) * K + k0);
    }
    __syncthreads(); // previous iteration's LDS reads complete
#pragma unroll
    for (int p = 0; p < 4; ++p) {
      short4 h, l;
      split4(av[p], &h, &l);
      *(short4*)&Ah[r8 + 32 * p][c8] = h;
      *(short4*)&Al[r8 + 32 * p][c8] = l;
      split4(wv[p], &h, &l);
      *(short4*)&Wh[r8 + 32 * p][c8] = h;
      *(short4*)&Wl[r8 + 32 * p][c8] = l;
    }
    __syncthreads();
#pragma unroll
    for (int kk = 0; kk < 32; kk += 16) {
      bf16x8 ah[2], al2[2], wh[2], wl2[2];
#pragma unroll
      for (int s = 0; s < 2; ++s) {
        const int ar = wm + (s << 5) + m32;
        const int wr = wn + (s << 5) + m32;
        const int kc = kk + (g << 3);
        ah[s]  = *(const bf16x8*)&Ah[ar][kc];
        al2[s] = *(const bf16x8*)&Al[ar][kc];
        wh[s]  = *(const bf16x8*)&Wh[wr][kc];
        wl2[s] = *(const bf16x8*)&Wl[wr][kc];
      }
#pragma unroll
      for (int si = 0; si < 2; ++si)
#pragma unroll
        for (int sj = 0; sj < 2; ++sj) {
          acc[si][sj] = __builtin_amdgcn_mfma_f32_32x32x16_bf16(al2[si], wh[sj], acc[si][sj], 0, 0, 0);
          acc[si][sj] = __builtin_amdgcn_mfma_f32_32x32x16_bf16(ah[si], wl2[sj], acc[si][sj], 0, 0, 0);
          acc[si][sj] = __builtin_amdgcn_mfma_f32_32x32x16_bf16(ah[si], wh[sj], acc[si][sj], 0, 0, 0);
        }
    }
  }

  // epilogue: C/D layout col=lane&31, row=(reg&3)+8*(reg>>2)+4*g
#pragma unroll
  for (int si = 0; si < 2; ++si)
#pragma unroll
    for (int sj = 0; sj < 2; ++sj) {
      const int col = bn + wn + (sj << 5) + m32;
      const float bv = bias[col];
#pragma unroll
      for (int reg = 0; reg < 16; ++reg) {
        const int row = bm + wm + (si << 5) + (g << 2) + (reg & 3) + ((reg >> 2) << 3);
        C[(size_t)row * N + col] = acc[si][sj][reg] + bv;
      }
    }
}

// ---------------------------------------------------------------------------
// Flash attention, fp32. One block per (b, h, 64-row Q tile).
// R2 change: P stored row-major [q][k] with float4 writes (was transposed
// scalar writes = 16-way bank conflict); Vs/Ps padded to stride 68.
// ---------------------------------------------------------------------------
__global__ __launch_bounds__(256) void flash_attn(const float* Q, const float* Kp,
                                                  const float* Vp, float* O) {
  __shared__ float Qs[64][64]; // [d][r], pre-scaled
  __shared__ float Ks[64][64]; // [d][c]
  __shared__ float Vs[64][68]; // [j][d], padded
  __shared__ float Ps[64][68]; // [q][k], padded
  const int tid = threadIdx.x;
  const int qt  = blockIdx.x << 6;
  const int bh  = blockIdx.y;
  const int b   = bh >> 4;
  const int h   = bh & 15;
  const size_t base = (size_t)b * Ss * Ee + (size_t)h * Dd;
  const int tx = tid & 15, ty = tid >> 4;
  const int lr = tid >> 2;        // 0..63
  const int lc = (tid & 3) << 4;  // 0,16,32,48

  { // load+scale Q tile
    const float* qp = Q + base + (size_t)(qt + lr) * Ee + lc;
#pragma unroll
    for (int i = 0; i < 4; ++i) {
      float4 v = *(const float4*)(qp + 4 * i);
      const int c = lc + 4 * i;
      Qs[c+0][lr] = v.x * 0.125f;
      Qs[c+1][lr] = v.y * 0.125f;
      Qs[c+2][lr] = v.z * 0.125f;
      Qs[c+3][lr] = v.w * 0.125f;
    }
  }

  float o[4][4] = {};
  float m_[4] = {-INFINITY, -INFINITY, -INFINITY, -INFINITY};
  float l_[4] = {0.f, 0.f, 0.f, 0.f};

  for (int kt = 0; kt < Ss; kt += 64) {
    const float* kp = Kp + base + (size_t)(kt + lr) * Ee + lc;
    const float* vp = Vp + base + (size_t)(kt + lr) * Ee + lc;
    float4 kv[4], vv[4];
#pragma unroll
    for (int i = 0; i < 4; ++i) {
      kv[i] = *(const float4*)(kp + 4 * i);
      vv[i] = *(const float4*)(vp + 4 * i);
    }
    __syncthreads(); // prev tile's reads of Ks/Vs/Ps complete
#pragma unroll
    for (int i = 0; i < 4; ++i) {
      const int c = lc + 4 * i;
      Ks[c+0][lr] = kv[i].x; Ks[c+1][lr] = kv[i].y;
      Ks[c+2][lr] = kv[i].z; Ks[c+3][lr] = kv[i].w;
      *(float4*)(&Vs[lr][c]) = vv[i];
    }
    __syncthreads();

    // Sc = (Q/8) K^T  -- 4x4 per thread
    float sc[4][4] = {};
#pragma unroll 8
    for (int d = 0; d < 64; ++d) {
      float4 qv = *(const float4*)(&Qs[d][ty << 2]);
      float4 kk = *(const float4*)(&Ks[d][tx << 2]);
      float qa[4] = {qv.x, qv.y, qv.z, qv.w};
      float ka[4] = {kk.x, kk.y, kk.z, kk.w};
#pragma unroll
      for (int i = 0; i < 4; ++i)
#pragma unroll
        for (int j = 0; j < 4; ++j)
          sc[i][j] += qa[i] * ka[j];
    }

    // online softmax (rows live in 16-lane shuffle groups)
#pragma unroll
    for (int i = 0; i < 4; ++i) {
      float mt = fmaxf(fmaxf(sc[i][0], sc[i][1]), fmaxf(sc[i][2], sc[i][3]));
#pragma unroll
      for (int off = 1; off < 16; off <<= 1) mt = fmaxf(mt, __shfl_xor(mt, off, 16));
      const float mn = fmaxf(m_[i], mt);
      const float alpha = __expf(m_[i] - mn);
      m_[i] = mn;
      float rs = 0.f;
#pragma unroll
      for (int j = 0; j < 4; ++j) { sc[i][j] = __expf(sc[i][j] - mn); rs += sc[i][j]; }
#pragma unroll
      for (int off = 1; off < 16; off <<= 1) rs += __shfl_xor(rs, off, 16);
      l_[i] = alpha * l_[i] + rs;
#pragma unroll
      for (int j = 0; j < 4; ++j) o[i][j] *= alpha;
    }

    // P -> LDS, row-major [q][k], float4 stores (bank-uniform)
#pragma unroll
    for (int i = 0; i < 4; ++i) {
      float4 pr;
      pr.x = sc[i][0]; pr.y = sc[i][1]; pr.z = sc[i][2]; pr.w = sc[i][3];
      *(float4*)(&Ps[(ty << 2) + i][tx << 2]) = pr;
    }
    __syncthreads();

    // O += P V  : o[i][j] += sum_k P[4ty+i][k] * V[k][4tx+j]
#pragma unroll 4
    for (int k0 = 0; k0 < 64; k0 += 4) {
      float4 p[4], vz[4];
#pragma unroll
      for (int i = 0; i < 4; ++i) p[i] = *(const float4*)(&Ps[(ty << 2) + i][k0]);
#pragma unroll
      for (int kk2 = 0; kk2 < 4; ++kk2) vz[kk2] = *(const float4*)(&Vs[k0 + kk2][tx << 2]);
#pragma unroll
      for (int i = 0; i < 4; ++i) {
        float pa[4] = {p[i].x, p[i].y, p[i].z, p[i].w};
#pragma unroll
        for (int kk2 = 0; kk2 < 4; ++kk2) {
          o[i][0] += pa[kk2] * vz[kk2].x;
          o[i][1] += pa[kk2] * vz[kk2].y;
          o[i][2] += pa[kk2] * vz[kk2].z;
          o[i][3] += pa[kk2] * vz[kk2].w;
        }
      }
    }
  }

  // epilogue: normalize, write (O aliases Q region this block already consumed)
#pragma unroll
  for (int i = 0; i < 4; ++i) {
    const float inv = 1.0f / l_[i];
    float4 ov;
    ov.x = o[i][0] * inv; ov.y = o[i][1] * inv;
    ov.z = o[i][2] * inv; ov.w = o[i][3] * inv;
    *(float4*)(O + base + (size_t)(qt + (ty << 2) + i) * Ee + (tx << 2)) = ov;
  }
}

extern "C" void kernel_launch(void* const* d_in, const int* in_sizes, int n_in,
                              void* d_out, int out_size, void* d_ws, size_t ws_size,
                              hipStream_t stream) {
  const float* x  = (const float*)d_in[0];
  const float* Wq = (const float*)d_in[1];
  const float* bq = (const float*)d_in[2];
  const float* Wk = (const float*)d_in[3];
  const float* bk = (const float*)d_in[4];
  const float* Wv = (const float*)d_in[5];
  const float* bv = (const float*)d_in[6];
  const float* Wo = (const float*)d_in[7];
  const float* bo = (const float*)d_in[8];
  float* out = (float*)d_out;

  const size_t nBSE = (size_t)Bb * Ss * Ee; // 32 MB each
  float* qbuf = (float*)d_ws;
  float* kbuf = qbuf + nBSE;
  float* vbuf = kbuf + nBSE;

  dim3 gg(Mtot / 128, Ee / 128);
  gemm_mfma<<<gg, 256, 0, stream>>>(x, Wq, bq, qbuf, Mtot, Ee, Ee);
  gemm_mfma<<<gg, 256, 0, stream>>>(x, Wk, bk, kbuf, Mtot, Ee, Ee);
  gemm_mfma<<<gg, 256, 0, stream>>>(x, Wv, bv, vbuf, Mtot, Ee, Ee);
  flash_attn<<<dim3(Ss / 64, Bb * Hh), 256, 0, stream>>>(qbuf, kbuf, vbuf, qbuf);
  gemm_mfma<<<gg, 256, 0, stream>>>(qbuf, Wo, bo, out, Mtot, Ee, Ee);
}

// Round 3
// 514.213 us; speedup vs baseline: 4.1748x; 2.8490x over previous
//
#include <hip/hip_runtime.h>
#include <math.h>

#define Bb 4
#define Ss 2048
#define Ee 1024
#define Hh 16
#define Dd 64

static constexpr int Mtot = Bb * Ss; // 8192

typedef __bf16 bf16x8 __attribute__((ext_vector_type(8)));
typedef float  f32x16 __attribute__((ext_vector_type(16)));

// Truncation split: a = hi + lo (hi = top-16 bits, lo = bf16(a - hi)).
__device__ __forceinline__ void split4(const float4 v, short4* h, short4* l) {
  unsigned u;
  u = __float_as_uint(v.x); h->x = (short)(u >> 16);
  l->x = (short)(__float_as_uint(v.x - __uint_as_float(u & 0xFFFF0000u)) >> 16);
  u = __float_as_uint(v.y); h->y = (short)(u >> 16);
  l->y = (short)(__float_as_uint(v.y - __uint_as_float(u & 0xFFFF0000u)) >> 16);
  u = __float_as_uint(v.z); h->z = (short)(u >> 16);
  l->z = (short)(__float_as_uint(v.z - __uint_as_float(u & 0xFFFF0000u)) >> 16);
  u = __float_as_uint(v.w); h->w = (short)(u >> 16);
  l->w = (short)(__float_as_uint(v.w - __uint_as_float(u & 0xFFFF0000u)) >> 16);
}

__device__ __forceinline__ short rne1(float x) {
  unsigned u = __float_as_uint(x);
  return (short)((u + 0x7FFFu + ((u >> 16) & 1u)) >> 16);
}
__device__ __forceinline__ short4 rne4(const float4 v) {
  short4 r;
  r.x = rne1(v.x); r.y = rne1(v.y); r.z = rne1(v.z); r.w = rne1(v.w);
  return r;
}

// ---------------------------------------------------------------------------
// Split-bf16 MFMA GEMM: C[M,N] = A[M,K] @ W[N,K]^T + bias[N]  (unchanged R2)
// ---------------------------------------------------------------------------
__global__ __launch_bounds__(256) void gemm_mfma(const float* __restrict__ A,
                                                 const float* __restrict__ W,
                                                 const float* __restrict__ bias,
                                                 float* __restrict__ C,
                                                 int M, int N, int K) {
  __shared__ short Ah[128][40];
  __shared__ short Al[128][40];
  __shared__ short Wh[128][40];
  __shared__ short Wl[128][40];

  const int tid = threadIdx.x;
  const int bm  = blockIdx.x << 7;
  const int bn  = blockIdx.y << 7;
  const int r8  = tid >> 3;
  const int c8  = (tid & 7) << 2;
  const int lane = tid & 63;
  const int w    = tid >> 6;
  const int wm   = (w & 1) << 6;
  const int wn   = (w >> 1) << 6;
  const int m32  = lane & 31;
  const int g    = lane >> 5;

  const float* Ap = A + (size_t)(bm + r8) * K + c8;
  const float* Wp = W + (size_t)(bn + r8) * K + c8;

  f32x16 acc[2][2] = {};

  for (int k0 = 0; k0 < K; k0 += 32) {
    float4 av[4], wv[4];
#pragma unroll
    for (int p = 0; p < 4; ++p) {
      av[p] = *(const float4*)(Ap + (size_t)(32 * p) * K + k0);
      wv[p] = *(const float4*)(Wp + (size_t)(32 * p) * K + k0);
    }
    __syncthreads();
#pragma unroll
    for (int p = 0; p < 4; ++p) {
      short4 h, l;
      split4(av[p], &h, &l);
      *(short4*)&Ah[r8 + 32 * p][c8] = h;
      *(short4*)&Al[r8 + 32 * p][c8] = l;
      split4(wv[p], &h, &l);
      *(short4*)&Wh[r8 + 32 * p][c8] = h;
      *(short4*)&Wl[r8 + 32 * p][c8] = l;
    }
    __syncthreads();
#pragma unroll
    for (int kk = 0; kk < 32; kk += 16) {
      bf16x8 ah[2], al2[2], wh[2], wl2[2];
#pragma unroll
      for (int s = 0; s < 2; ++s) {
        const int ar = wm + (s << 5) + m32;
        const int wr = wn + (s << 5) + m32;
        const int kc = kk + (g << 3);
        ah[s]  = *(const bf16x8*)&Ah[ar][kc];
        al2[s] = *(const bf16x8*)&Al[ar][kc];
        wh[s]  = *(const bf16x8*)&Wh[wr][kc];
        wl2[s] = *(const bf16x8*)&Wl[wr][kc];
      }
#pragma unroll
      for (int si = 0; si < 2; ++si)
#pragma unroll
        for (int sj = 0; sj < 2; ++sj) {
          acc[si][sj] = __builtin_amdgcn_mfma_f32_32x32x16_bf16(al2[si], wh[sj], acc[si][sj], 0, 0, 0);
          acc[si][sj] = __builtin_amdgcn_mfma_f32_32x32x16_bf16(ah[si], wl2[sj], acc[si][sj], 0, 0, 0);
          acc[si][sj] = __builtin_amdgcn_mfma_f32_32x32x16_bf16(ah[si], wh[sj], acc[si][sj], 0, 0, 0);
        }
    }
  }

#pragma unroll
  for (int si = 0; si < 2; ++si)
#pragma unroll
    for (int sj = 0; sj < 2; ++sj) {
      const int col = bn + wn + (sj << 5) + m32;
      const float bv = bias[col];
#pragma unroll
      for (int reg = 0; reg < 16; ++reg) {
        const int row = bm + wm + (si << 5) + (g << 2) + (reg & 3) + ((reg >> 2) << 3);
        C[(size_t)row * N + col] = acc[si][sj][reg] + bv;
      }
    }
}

// ---------------------------------------------------------------------------
// Same GEMM but writes the result TRANSPOSED per head: vt[b][h][d][s].
// Rows of a reg-quad are s-consecutive -> float4 stores along s.
// ---------------------------------------------------------------------------
__global__ __launch_bounds__(256) void gemm_mfma_vt(const float* __restrict__ A,
                                                    const float* __restrict__ W,
                                                    const float* __restrict__ bias,
                                                    float* __restrict__ VT,
                                                    int M, int N, int K) {
  __shared__ short Ah[128][40];
  __shared__ short Al[128][40];
  __shared__ short Wh[128][40];
  __shared__ short Wl[128][40];

  const int tid = threadIdx.x;
  const int bm  = blockIdx.x << 7;
  const int bn  = blockIdx.y << 7;
  const int r8  = tid >> 3;
  const int c8  = (tid & 7) << 2;
  const int lane = tid & 63;
  const int w    = tid >> 6;
  const int wm   = (w & 1) << 6;
  const int wn   = (w >> 1) << 6;
  const int m32  = lane & 31;
  const int g    = lane >> 5;

  const float* Ap = A + (size_t)(bm + r8) * K + c8;
  const float* Wp = W + (size_t)(bn + r8) * K + c8;

  f32x16 acc[2][2] = {};

  for (int k0 = 0; k0 < K; k0 += 32) {
    float4 av[4], wv[4];
#pragma unroll
    for (int p = 0; p < 4; ++p) {
      av[p] = *(const float4*)(Ap + (size_t)(32 * p) * K + k0);
      wv[p] = *(const float4*)(Wp + (size_t)(32 * p) * K + k0);
    }
    __syncthreads();
#pragma unroll
    for (int p = 0; p < 4; ++p) {
      short4 h, l;
      split4(av[p], &h, &l);
      *(short4*)&Ah[r8 + 32 * p][c8] = h;
      *(short4*)&Al[r8 + 32 * p][c8] = l;
      split4(wv[p], &h, &l);
      *(short4*)&Wh[r8 + 32 * p][c8] = h;
      *(short4*)&Wl[r8 + 32 * p][c8] = l;
    }
    __syncthreads();
#pragma unroll
    for (int kk = 0; kk < 32; kk += 16) {
      bf16x8 ah[2], al2[2], wh[2], wl2[2];
#pragma unroll
      for (int s = 0; s < 2; ++s) {
        const int ar = wm + (s << 5) + m32;
        const int wr = wn + (s << 5) + m32;
        const int kc = kk + (g << 3);
        ah[s]  = *(const bf16x8*)&Ah[ar][kc];
        al2[s] = *(const bf16x8*)&Al[ar][kc];
        wh[s]  = *(const bf16x8*)&Wh[wr][kc];
        wl2[s] = *(const bf16x8*)&Wl[wr][kc];
      }
#pragma unroll
      for (int si = 0; si < 2; ++si)
#pragma unroll
        for (int sj = 0; sj < 2; ++sj) {
          acc[si][sj] = __builtin_amdgcn_mfma_f32_32x32x16_bf16(al2[si], wh[sj], acc[si][sj], 0, 0, 0);
          acc[si][sj] = __builtin_amdgcn_mfma_f32_32x32x16_bf16(ah[si], wl2[sj], acc[si][sj], 0, 0, 0);
          acc[si][sj] = __builtin_amdgcn_mfma_f32_32x32x16_bf16(ah[si], wh[sj], acc[si][sj], 0, 0, 0);
        }
    }
  }

  const int bmS = bm & (Ss - 1);
  const int bq  = bm >> 11; // batch index (128-row tiles never straddle b)
#pragma unroll
  for (int si = 0; si < 2; ++si)
#pragma unroll
    for (int sj = 0; sj < 2; ++sj) {
      const int col = bn + wn + (sj << 5) + m32;
      const int hh = col >> 6, dd = col & 63;
      const float bvv = bias[col];
      float* vrow = VT + ((size_t)((bq * Hh + hh) * Dd + dd)) * Ss;
#pragma unroll
      for (int rq = 0; rq < 4; ++rq) {
        const int s0 = bmS + wm + (si << 5) + (g << 2) + (rq << 3);
        float4 o;
        o.x = acc[si][sj][rq * 4 + 0] + bvv;
        o.y = acc[si][sj][rq * 4 + 1] + bvv;
        o.z = acc[si][sj][rq * 4 + 2] + bvv;
        o.w = acc[si][sj][rq * 4 + 3] + bvv;
        *(float4*)(vrow + s0) = o;
      }
    }
}

// ---------------------------------------------------------------------------
// MFMA flash attention. Block = one (b,h) x 128 Q rows, 4 waves, KV tiles of
// 64. S^T = K.Q^T (Q split hi/lo, K bf16-RNE); softmax per-lane (col=q);
// P re-layout C->B via shfl_xor(32); O^T += V^T.P (V from vt[b][h][d][s]).
// One 36 KB LDS buffer reused: Q staging -> K/Vt tiles -> O epilogue.
// ---------------------------------------------------------------------------
__global__ __launch_bounds__(256) void flash_mfma(const float* __restrict__ Q,
                                                  const float* __restrict__ Kp,
                                                  const float* __restrict__ Vt,
                                                  float* __restrict__ O) {
  __shared__ unsigned short smem[18432]; // 36864 B
  unsigned short* Qh = smem;             // [128][72]
  unsigned short* Ql = smem + 9216;
  unsigned short* Kh = smem;             // [64][72]  (after Q frags cached)
  unsigned short* Vh = smem + 4608;      // [64][72]

  const int tid = threadIdx.x;
  const int qt  = blockIdx.x << 7;
  const int bh  = blockIdx.y;
  const size_t qkbase = (size_t)(bh >> 4) * Ss * Ee + (size_t)(bh & 15) * Dd;
  const size_t vtbase = (size_t)bh * Dd * Ss;
  const int lane = tid & 63, w = tid >> 6;
  const int m32 = lane & 31, g = lane >> 5;
  const int sr = tid >> 2;        // 0..63
  const int sc = (tid & 3) << 4;  // 0,16,32,48

  // ---- stage Q tile (scaled by 1/sqrt(D)=1/8), split hi/lo
#pragma unroll
  for (int half = 0; half < 2; ++half) {
    const int qr = (half << 6) + sr;
    const float* qp = Q + qkbase + (size_t)(qt + qr) * Ee + sc;
#pragma unroll
    for (int i = 0; i < 4; ++i) {
      float4 v = *(const float4*)(qp + 4 * i);
      v.x *= 0.125f; v.y *= 0.125f; v.z *= 0.125f; v.w *= 0.125f;
      short4 hh, ll;
      split4(v, &hh, &ll);
      *(short4*)&Qh[qr * 72 + sc + 4 * i] = hh;
      *(short4*)&Ql[qr * 72 + sc + 4 * i] = ll;
    }
  }
  __syncthreads();
  // cache this wave's Q B-frags (rows w*32+m32) in registers for the whole loop
  bf16x8 qfh[4], qfl[4];
  {
    const int qrow = (w << 5) + m32;
#pragma unroll
    for (int c = 0; c < 4; ++c) {
      qfh[c] = *(const bf16x8*)&Qh[qrow * 72 + (c << 4) + (g << 3)];
      qfl[c] = *(const bf16x8*)&Ql[qrow * 72 + (c << 4) + (g << 3)];
    }
  }

  f32x16 acc_o[2] = {}; // O^T: D[d, q], col=lane=q
  float m_ = -INFINITY, l_ = 0.f;

  for (int kt = 0; kt < Ss; kt += 64) {
    float4 kv[4], vv[4];
    const float* kp = Kp + qkbase + (size_t)(kt + sr) * Ee + sc;
    const float* vp = Vt + vtbase + (size_t)sr * Ss + kt + sc; // row d=sr
#pragma unroll
    for (int i = 0; i < 4; ++i) {
      kv[i] = *(const float4*)(kp + 4 * i);
      vv[i] = *(const float4*)(vp + 4 * i);
    }
    __syncthreads(); // prior tile's frag reads (and Q frag reads) complete
#pragma unroll
    for (int i = 0; i < 4; ++i) {
      *(short4*)&Kh[sr * 72 + sc + 4 * i] = rne4(kv[i]);
      *(short4*)&Vh[sr * 72 + sc + 4 * i] = rne4(vv[i]);
    }
    __syncthreads();

    // ---- scores S^T = K.(Qh+Ql)^T : D[k, q]
    float p[2][16];
    float mt_ = -INFINITY;
#pragma unroll
    for (int mt = 0; mt < 2; ++mt) {
      f32x16 a = {};
#pragma unroll
      for (int c = 0; c < 4; ++c) {
        bf16x8 kf = *(const bf16x8*)&Kh[((mt << 5) + m32) * 72 + (c << 4) + (g << 3)];
        a = __builtin_amdgcn_mfma_f32_32x32x16_bf16(kf, qfh[c], a, 0, 0, 0);
        a = __builtin_amdgcn_mfma_f32_32x32x16_bf16(kf, qfl[c], a, 0, 0, 0);
      }
#pragma unroll
      for (int r = 0; r < 16; ++r) {
        p[mt][r] = a[r];
        mt_ = fmaxf(mt_, a[r]);
      }
    }
    mt_ = fmaxf(mt_, __shfl_xor(mt_, 32)); // lanes l, l^32 share col q
    const float mn = fmaxf(m_, mt_);
    const float alpha = __expf(m_ - mn);
    m_ = mn;
    float rs = 0.f;
#pragma unroll
    for (int mt = 0; mt < 2; ++mt)
#pragma unroll
      for (int r = 0; r < 16; ++r) {
        float e = __expf(p[mt][r] - mn);
        e = __uint_as_float(__float_as_uint(e) & 0xFFFF0000u); // truncate to bf16
        p[mt][r] = e;
        rs += e; // sum of ROUNDED p: normalization bias cancels
      }
    rs += __shfl_xor(rs, 32);
    l_ = alpha * l_ + rs;
#pragma unroll
    for (int dt = 0; dt < 2; ++dt)
#pragma unroll
      for (int r = 0; r < 16; ++r) acc_o[dt][r] *= alpha;

    // ---- PV: O^T += V^T . P  (P: C-layout -> B-frag via shfl_xor 32)
#pragma unroll
    for (int c = 0; c < 4; ++c) {
      const int mt = c >> 1, b8 = (c & 1) << 3;
      float tsh[8];
#pragma unroll
      for (int i = 0; i < 8; ++i) tsh[i] = __shfl_xor(p[mt][b8 + i], 32);
      union { unsigned short u[8]; bf16x8 v; } pf;
#pragma unroll
      for (int j = 0; j < 4; ++j) {
        // g=0: {own[b..b+3], partner[b..b+3]}; g=1: {partner[b+4..b+7], own[b+4..b+7]}
        const float a0 = g ? tsh[4 + j] : p[mt][b8 + j];
        const float a1 = g ? p[mt][b8 + 4 + j] : tsh[j];
        pf.u[j]     = (unsigned short)(__float_as_uint(a0) >> 16);
        pf.u[4 + j] = (unsigned short)(__float_as_uint(a1) >> 16);
      }
#pragma unroll
      for (int dt = 0; dt < 2; ++dt) {
        bf16x8 vf = *(const bf16x8*)&Vh[((dt << 5) + m32) * 72 + (c << 4) + (g << 3)];
        acc_o[dt] = __builtin_amdgcn_mfma_f32_32x32x16_bf16(vf, pf.v, acc_o[dt], 0, 0, 0);
      }
    }
  }

  // ---- epilogue: O^T regs -> LDS [q][d] -> coalesced float4 global stores
  __syncthreads();
  float* Of = (float*)smem; // [128][68] floats = 34816 B
  const float inv = 1.0f / l_;
#pragma unroll
  for (int dt = 0; dt < 2; ++dt)
#pragma unroll
    for (int r = 0; r < 16; ++r) {
      const int d = (dt << 5) + (r & 3) + ((r >> 2) << 3) + (g << 2);
      Of[((w << 5) + m32) * 68 + d] = acc_o[dt][r] * inv;
    }
  __syncthreads();
  const int orow = tid >> 1;
  const int oc = (tid & 1) << 5;
  float* op = O + qkbase + (size_t)(qt + orow) * Ee + oc;
#pragma unroll
  for (int i = 0; i < 8; ++i)
    *(float4*)(op + 4 * i) = *(const float4*)&Of[orow * 68 + oc + 4 * i];
}

extern "C" void kernel_launch(void* const* d_in, const int* in_sizes, int n_in,
                              void* d_out, int out_size, void* d_ws, size_t ws_size,
                              hipStream_t stream) {
  const float* x  = (const float*)d_in[0];
  const float* Wq = (const float*)d_in[1];
  const float* bq = (const float*)d_in[2];
  const float* Wk = (const float*)d_in[3];
  const float* bk = (const float*)d_in[4];
  const float* Wv = (const float*)d_in[5];
  const float* bv = (const float*)d_in[6];
  const float* Wo = (const float*)d_in[7];
  const float* bo = (const float*)d_in[8];
  float* out = (float*)d_out;

  const size_t nBSE = (size_t)Bb * Ss * Ee; // 32 MB each
  float* qbuf  = (float*)d_ws;
  float* kbuf  = qbuf + nBSE;
  float* vtbuf = kbuf + nBSE;

  dim3 gg(Mtot / 128, Ee / 128);
  gemm_mfma<<<gg, 256, 0, stream>>>(x, Wq, bq, qbuf, Mtot, Ee, Ee);
  gemm_mfma<<<gg, 256, 0, stream>>>(x, Wk, bk, kbuf, Mtot, Ee, Ee);
  gemm_mfma_vt<<<gg, 256, 0, stream>>>(x, Wv, bv, vtbuf, Mtot, Ee, Ee);
  flash_mfma<<<dim3(Ss / 128, Bb * Hh), 256, 0, stream>>>(qbuf, kbuf, vtbuf, qbuf);
  gemm_mfma<<<gg, 256, 0, stream>>>(qbuf, Wo, bo, out, Mtot, Ee, Ee);
}